// Round 13
// baseline (184.980 us; speedup 1.0000x reference)
//
#include <hip/hip_runtime.h>

#define HW_  16384   // H*W = 128*128
#define NPX  32768   // B*H*W

__device__ __forceinline__ float prelu_(float x, float a) { return x >= 0.f ? x : a * x; }

// ---------------- K_front: x1 = prelu(conv1(x)), f = relu(wr·x1), zp = zpool(f) ----
__global__ __launch_bounds__(256, 3) void k_front(const float* __restrict__ x,
        const float* __restrict__ w1, const float* __restrict__ b1,
        const float* __restrict__ a1p, const float* __restrict__ wr,
        const float* __restrict__ br, float* __restrict__ x1,
        float* __restrict__ f, float* __restrict__ zp) {
    __shared__ float sA[12544];        // 50.2 KB, two overlay regions
    float* xs  = sA;                   // 4096: [ch64][px64]
    float* wT1 = sA + 4096;            // 8448: [o64][c] stride 132
    int p0 = blockIdx.x << 6;
    int b = p0 >> 14, hw0 = p0 & 16383;

    for (int e = threadIdx.x; e < 8192; e += 256) {
        int o = e >> 7, c = e & 127;
        wT1[o * 132 + c] = w1[e];
    }
    int pq = threadIdx.x & 15;
    int og = threadIdx.x >> 4;
    const float a1 = a1p[0];
    float4 acc[4];
    #pragma unroll
    for (int u = 0; u < 4; ++u) { float bv = b1[og * 4 + u]; acc[u] = make_float4(bv, bv, bv, bv); }
    const float* xb = x + (b << 21) + hw0;
    #pragma unroll 1
    for (int half = 0; half < 2; ++half) {
        float4 xv[4];
        #pragma unroll
        for (int i = 0; i < 4; ++i) {
            int e = threadIdx.x + (i << 8);
            xv[i] = *(const float4*)&xb[((half * 64 + (e >> 4)) << 14) + ((e & 15) << 2)];
        }
        __syncthreads();
        #pragma unroll
        for (int i = 0; i < 4; ++i) {
            int e = threadIdx.x + (i << 8);
            *(float4*)&xs[((e >> 4) << 6) + ((e & 15) << 2)] = xv[i];
        }
        __syncthreads();
        #pragma unroll 4
        for (int c4 = 0; c4 < 16; ++c4) {
            float4 taps[4];
            #pragma unroll
            for (int j = 0; j < 4; ++j)
                taps[j] = *(const float4*)&xs[((c4 * 4 + j) << 6) + (pq << 2)];
            #pragma unroll
            for (int u = 0; u < 4; ++u) {
                float4 wv = *(const float4*)&wT1[(og * 4 + u) * 132 + half * 64 + c4 * 4];
                acc[u].x = fmaf(wv.x, taps[0].x, acc[u].x); acc[u].y = fmaf(wv.x, taps[0].y, acc[u].y);
                acc[u].z = fmaf(wv.x, taps[0].z, acc[u].z); acc[u].w = fmaf(wv.x, taps[0].w, acc[u].w);
                acc[u].x = fmaf(wv.y, taps[1].x, acc[u].x); acc[u].y = fmaf(wv.y, taps[1].y, acc[u].y);
                acc[u].z = fmaf(wv.y, taps[1].z, acc[u].z); acc[u].w = fmaf(wv.y, taps[1].w, acc[u].w);
                acc[u].x = fmaf(wv.z, taps[2].x, acc[u].x); acc[u].y = fmaf(wv.z, taps[2].y, acc[u].y);
                acc[u].z = fmaf(wv.z, taps[2].z, acc[u].z); acc[u].w = fmaf(wv.z, taps[2].w, acc[u].w);
                acc[u].x = fmaf(wv.w, taps[3].x, acc[u].x); acc[u].y = fmaf(wv.w, taps[3].y, acc[u].y);
                acc[u].z = fmaf(wv.w, taps[3].z, acc[u].z); acc[u].w = fmaf(wv.w, taps[3].w, acc[u].w);
            }
        }
    }
    float4 res[4];
    #pragma unroll
    for (int u = 0; u < 4; ++u) {
        res[u].x = prelu_(acc[u].x, a1); res[u].y = prelu_(acc[u].y, a1);
        res[u].z = prelu_(acc[u].z, a1); res[u].w = prelu_(acc[u].w, a1);
        *(float4*)(x1 + ((b * 64 + og * 4 + u) << 14) + hw0 + (pq << 2)) = res[u];
    }
    __syncthreads();
    float* x1t = sA;                   // 4352: [c64][px] stride 68
    float* wrT = sA + 4352;            // 2080: [fo32][c] stride 65
    float* ft  = sA + 6432;            // 2176: [fo32][px] stride 68
    #pragma unroll
    for (int u = 0; u < 4; ++u)
        *(float4*)&x1t[(og * 4 + u) * 68 + (pq << 2)] = res[u];
    for (int e = threadIdx.x; e < 2048; e += 256) {
        int fo = e >> 6, c = e & 63;
        wrT[fo * 65 + c] = wr[e];
    }
    __syncthreads();
    int pq2 = threadIdx.x & 15;
    int fg = threadIdx.x >> 4;
    float4 fa[2];
    #pragma unroll
    for (int u = 0; u < 2; ++u) { float bv = br[fg * 2 + u]; fa[u] = make_float4(bv, bv, bv, bv); }
    #pragma unroll 4
    for (int c = 0; c < 64; ++c) {
        float4 tap = *(const float4*)&x1t[c * 68 + (pq2 << 2)];
        #pragma unroll
        for (int u = 0; u < 2; ++u) {
            float wv = wrT[(fg * 2 + u) * 65 + c];
            fa[u].x = fmaf(wv, tap.x, fa[u].x);
            fa[u].y = fmaf(wv, tap.y, fa[u].y);
            fa[u].z = fmaf(wv, tap.z, fa[u].z);
            fa[u].w = fmaf(wv, tap.w, fa[u].w);
        }
    }
    #pragma unroll
    for (int u = 0; u < 2; ++u) {
        float4 r;
        r.x = fmaxf(fa[u].x, 0.f); r.y = fmaxf(fa[u].y, 0.f);
        r.z = fmaxf(fa[u].z, 0.f); r.w = fmaxf(fa[u].w, 0.f);
        *(float4*)(f + ((b * 32 + fg * 2 + u) << 14) + hw0 + (pq2 << 2)) = r;
        *(float4*)&ft[(fg * 2 + u) * 68 + (pq2 << 2)] = r;
    }
    __syncthreads();
    if (threadIdx.x < 64) {
        int px = threadIdx.x;
        float mx = ft[px], sm = ft[px];
        #pragma unroll
        for (int c = 1; c < 32; ++c) {
            float v = ft[c * 68 + px];
            mx = fmaxf(mx, v); sm += v;
        }
        zp[((b * 2 + 0) << 14) + hw0 + px] = mx;
        zp[((b * 2 + 1) << 14) + hw0 + px] = sm * (1.f / 32.f);
    }
}

// ---------------- K_mid2 v3: [0,256) invol ; [256,768) psec ; [768,896) attn ----
// invol: 16x32 tile, thread = 2 horiz px x 16 ch, x1 staged in two 8-ch chunks
// (taps via ds_read2/b64). psec: fs stride 20 (b128 taps), weights [o][ci][12].
__global__ __launch_bounds__(256, 3) void k_mid2(const float* __restrict__ x1,
        const float* __restrict__ f, const float* __restrict__ ws_,
        const float* __restrict__ bs, float* __restrict__ x2,
        const float* __restrict__ zp, const float* __restrict__ wp1,
        const float* __restrict__ bp1, const float* __restrict__ app,
        float* __restrict__ p1, const float* __restrict__ wa,
        const float* __restrict__ ba, float* __restrict__ attn,
        const float* __restrict__ a2p) {
    __shared__ float smem[9472];           // 37.9 KB union
    if (blockIdx.x < 256) {
        // ---- involution: group g x 16x32 px tile
        float* tile = smem;                // [8ch][22r][40]; ch stride 880
        int g = blockIdx.x >> 6;           // 0..3
        int t = blockIdx.x & 63;
        int b = t >> 5;
        int tl = t & 31;                   // 8 h-tiles x 4 w-tiles
        int th = tl >> 2, tw = tl & 3;
        int h0 = th * 16, w0 = tw * 32;
        int lh = threadIdx.x >> 4;         // row 0..15
        int pc = threadIdx.x & 15;         // col-pair -> cols 2pc, 2pc+1
        int hw = ((h0 + lh) << 7) + w0 + pc * 2;
        const float* fp = f + (b << 19) + hw;
        float2 fv[32];
        #pragma unroll
        for (int c = 0; c < 32; ++c) fv[c] = *(const float2*)&fp[c << 14];
        float2 acc[16];
        #pragma unroll
        for (int u = 0; u < 16; ++u) acc[u] = make_float2(0.f, 0.f);
        const float* x1g = x1 + ((b * 64 + g * 16) << 14);
        const float* wk = ws_ + g * 49 * 32;
        const float* bsg = bs + g * 49;
        #pragma unroll 1
        for (int ch = 0; ch < 2; ++ch) {
            __syncthreads();               // prev-chunk readers done
            #pragma unroll 1
            for (int rem = threadIdx.x; rem < 836; rem += 256) {   // 22 x 38 halo
                int r = rem / 38, cl = rem - r * 38;
                int hh = h0 + r - 3, ww = w0 + cl - 3;
                bool ok = (hh >= 0 && hh < 128 && ww >= 0 && ww < 128);
                const float* src = x1g + ((ch * 8) << 14) + (hh << 7) + ww;
                float v[8];
                #pragma unroll
                for (int c = 0; c < 8; ++c) v[c] = ok ? src[c << 14] : 0.f;
                float* dst = tile + r * 40 + cl;
                #pragma unroll
                for (int c = 0; c < 8; ++c) dst[c * 880] = v[c];
            }
            __syncthreads();
            const float* tap0 = tile + lh * 40 + pc * 2;
            #pragma unroll 1
            for (int di = 0; di < 7; ++di) {
                #pragma unroll 1
                for (int dj = 0; dj < 7; ++dj) {
                    int kk = di * 7 + dj;
                    float bsv = bsg[kk];
                    float2 kwv = make_float2(bsv, bsv);
                    const float* wkk = wk + kk * 32;
                    #pragma unroll
                    for (int c = 0; c < 32; ++c) {
                        float wc = wkk[c];
                        kwv.x = fmaf(wc, fv[c].x, kwv.x);
                        kwv.y = fmaf(wc, fv[c].y, kwv.y);
                    }
                    const float* tp = tap0 + di * 40 + dj;
                    #pragma unroll
                    for (int u = 0; u < 8; ++u) {
                        float t0 = tp[u * 880];            // fuses to ds_read2_b32
                        float t1 = tp[u * 880 + 1];
                        acc[ch * 8 + u].x = fmaf(kwv.x, t0, acc[ch * 8 + u].x);
                        acc[ch * 8 + u].y = fmaf(kwv.y, t1, acc[ch * 8 + u].y);
                    }
                }
            }
        }
        const float a2 = a2p[0];
        float* op = x2 + ((b * 64 + g * 16) << 14) + hw;
        #pragma unroll
        for (int u = 0; u < 16; ++u) {
            float2 r;
            r.x = prelu_(acc[u].x, a2); r.y = prelu_(acc[u].y, a2);
            *(float2*)&op[u << 14] = r;
        }
    } else if (blockIdx.x < 768) {
        // ---- psec conv3x3: 8x16 px tile x 16 outs (2 halves)
        float* fs = smem;                  // 6400: [ci][r(10)][cl] stride 20
        float* wT = smem + 6400;           // 3072: [o16][cl16][12]
        int bid = blockIdx.x - 256;
        int half = bid >> 8;
        int t = bid & 255;
        int b = t >> 7;
        int tl = t & 127;
        int th = tl >> 3, tw = tl & 7;
        int h0 = th * 8, w0 = tw * 16;
        int o0 = half * 16;
        const float* fb = f + (b << 19);
        #pragma unroll 1
        for (int rem = threadIdx.x; rem < 180; rem += 256) {
            int r = rem / 18, cl = rem - r * 18;
            int hh = h0 + r - 1, ww = w0 + cl - 1;
            bool ok = (hh >= 0 && hh < 128 && ww >= 0 && ww < 128);
            const float* src = fb + (hh << 7) + ww;
            float* dst = fs + r * 20 + cl;
            #pragma unroll 1
            for (int cb = 0; cb < 4; ++cb) {
                float v[8];
                #pragma unroll
                for (int c = 0; c < 8; ++c) v[c] = ok ? src[(cb * 8 + c) << 14] : 0.f;
                #pragma unroll
                for (int c = 0; c < 8; ++c) dst[(cb * 8 + c) * 200] = v[c];
            }
        }
        int pxq = threadIdx.x & 31;
        int rowq = pxq >> 2, colq = pxq & 3;
        int oh = threadIdx.x >> 5;         // 0..7 -> outs o0+oh*2, +1
        const float ap = app[0];
        float acc[2][4];
        #pragma unroll
        for (int o = 0; o < 2; ++o) {
            float bv = bp1[o0 + oh * 2 + o];
            #pragma unroll
            for (int px = 0; px < 4; ++px) acc[o][px] = bv;
        }
        const float* fsb = fs + rowq * 20 + colq * 4;
        #pragma unroll 1
        for (int cih = 0; cih < 2; ++cih) {
            __syncthreads();               // fs ready / prev-chunk wT reads done
            #pragma unroll 1
            for (int e = threadIdx.x; e < 2304; e += 256) {
                int o = e / 144, rem = e - o * 144;
                int cl_ = rem / 9, k = rem - cl_ * 9;
                wT[o * 192 + cl_ * 12 + k] = wp1[(o0 + o) * 288 + cih * 144 + rem];
            }
            __syncthreads();
            #pragma unroll 1
            for (int cl_ = 0; cl_ < 16; ++cl_) {
                int ci = cih * 16 + cl_;
                const float* base = fsb + ci * 200;
                float tap[3][6];
                #pragma unroll
                for (int r = 0; r < 3; ++r) {
                    float4 t4 = *(const float4*)&base[r * 20];        // b128
                    float2 t2 = *(const float2*)&base[r * 20 + 4];    // b64
                    tap[r][0] = t4.x; tap[r][1] = t4.y; tap[r][2] = t4.z;
                    tap[r][3] = t4.w; tap[r][4] = t2.x; tap[r][5] = t2.y;
                }
                const float* wb0 = &wT[(oh * 2 + 0) * 192 + cl_ * 12];
                const float* wb1 = &wT[(oh * 2 + 1) * 192 + cl_ * 12];
                float4 wa0 = *(const float4*)wb0;       // k 0..3 (b128 broadcast)
                float4 wa1 = *(const float4*)(wb0 + 4); // k 4..7
                float  wa2 = wb0[8];
                float4 wc0 = *(const float4*)wb1;
                float4 wc1 = *(const float4*)(wb1 + 4);
                float  wc2 = wb1[8];
                float w0a[9] = {wa0.x, wa0.y, wa0.z, wa0.w, wa1.x, wa1.y, wa1.z, wa1.w, wa2};
                float w1a[9] = {wc0.x, wc0.y, wc0.z, wc0.w, wc1.x, wc1.y, wc1.z, wc1.w, wc2};
                #pragma unroll
                for (int ki = 0; ki < 3; ++ki)
                    #pragma unroll
                    for (int kj = 0; kj < 3; ++kj) {
                        int k = ki * 3 + kj;
                        #pragma unroll
                        for (int px = 0; px < 4; ++px) {
                            float tv = tap[ki][px + kj];
                            acc[0][px] = fmaf(w0a[k], tv, acc[0][px]);
                            acc[1][px] = fmaf(w1a[k], tv, acc[1][px]);
                        }
                    }
            }
        }
        int hw = ((h0 + rowq) << 7) + w0 + colq * 4;
        #pragma unroll
        for (int o = 0; o < 2; ++o) {
            float4 r;
            r.x = prelu_(acc[o][0], ap); r.y = prelu_(acc[o][1], ap);
            r.z = prelu_(acc[o][2], ap); r.w = prelu_(acc[o][3], ap);
            *(float4*)(p1 + ((b * 32 + o0 + oh * 2 + o) << 14) + hw) = r;
        }
    } else {
        // ---- attn: 16x16 tile, zp halo in LDS
        float* zs = smem;                  // 2 x 506, stride 23
        int t = blockIdx.x - 768;          // 0..127
        int b = t >> 6;
        int tile = t & 63;
        int th = tile >> 3, tw = tile & 7;
        int h0 = th * 16, w0 = tw * 16;
        const float* zb = zp + (b << 15);
        #pragma unroll 1
        for (int rem = threadIdx.x; rem < 484; rem += 256) {
            int r = rem / 22, cl = rem - r * 22;
            int hh = h0 + r - 3, ww = w0 + cl - 3;
            bool ok = (hh >= 0 && hh < 128 && ww >= 0 && ww < 128);
            const float* src = zb + (hh << 7) + ww;
            float v0 = ok ? src[0] : 0.f;
            float v1 = ok ? src[HW_] : 0.f;
            zs[r * 23 + cl] = v0;
            zs[506 + r * 23 + cl] = v1;
        }
        __syncthreads();
        int lh = threadIdx.x >> 4, lw = threadIdx.x & 15;
        float acc = ba[0];
        #pragma unroll
        for (int c = 0; c < 2; ++c) {
            const float* zc = &zs[c * 506 + lh * 23 + lw];
            #pragma unroll
            for (int i = 0; i < 7; ++i)
                #pragma unroll
                for (int j = 0; j < 7; ++j)
                    acc = fmaf(wa[c * 49 + i * 7 + j], zc[i * 23 + j], acc);
        }
        attn[(b << 14) + ((h0 + lh) << 7) + w0 + lw] = 1.f / (1.f + expf(-acc));
    }
}

// ---------------- K_final: global-streaming (unchanged from round 12) ----------
__global__ __launch_bounds__(256, 4) void k_final(const float* __restrict__ x2p,
        const float* __restrict__ p1, const float* __restrict__ attn,
        const float* __restrict__ w2, const float* __restrict__ b2,
        const float* __restrict__ wp2, const float* __restrict__ bp2,
        float* __restrict__ out) {
    __shared__ float wT2[64 * 20];
    __shared__ float wTp[32 * 20];
    int split = blockIdx.x >> 7;
    int tile = blockIdx.x & 127;
    int p0 = tile << 8;
    int b = p0 >> 14, hw0 = p0 & 16383;
    int o0 = split * 16;

    for (int e = threadIdx.x; e < 1024; e += 256) {
        int o = e & 15, c = e >> 4;
        wT2[c * 20 + o] = w2[(o0 + o) * 64 + c];
    }
    for (int e = threadIdx.x; e < 512; e += 256) {
        int o = e & 15, c = e >> 4;
        wTp[c * 20 + o] = wp2[(o0 + o) * 32 + c];
    }
    int q4 = threadIdx.x & 63;
    int og = threadIdx.x >> 6;
    float b2v[4], bpv[4];
    #pragma unroll
    for (int u = 0; u < 4; ++u) { b2v[u] = b2[o0 + og * 4 + u]; bpv[u] = bp2[o0 + og * 4 + u]; }
    float4 acc[4];
    #pragma unroll
    for (int u = 0; u < 4; ++u) acc[u] = make_float4(0.f, 0.f, 0.f, 0.f);
    __syncthreads();

    const float* xb = x2p + (b << 20) + hw0 + (q4 << 2);
    #pragma unroll 1
    for (int cb = 0; cb < 8; ++cb) {
        float4 xv[8];
        #pragma unroll
        for (int j = 0; j < 8; ++j) xv[j] = *(const float4*)&xb[(cb * 8 + j) << 14];
        #pragma unroll
        for (int j = 0; j < 8; ++j) {
            float4 wv = *(const float4*)&wT2[(cb * 8 + j) * 20 + og * 4];
            acc[0].x = fmaf(wv.x, xv[j].x, acc[0].x); acc[0].y = fmaf(wv.x, xv[j].y, acc[0].y);
            acc[0].z = fmaf(wv.x, xv[j].z, acc[0].z); acc[0].w = fmaf(wv.x, xv[j].w, acc[0].w);
            acc[1].x = fmaf(wv.y, xv[j].x, acc[1].x); acc[1].y = fmaf(wv.y, xv[j].y, acc[1].y);
            acc[1].z = fmaf(wv.y, xv[j].z, acc[1].z); acc[1].w = fmaf(wv.y, xv[j].w, acc[1].w);
            acc[2].x = fmaf(wv.z, xv[j].x, acc[2].x); acc[2].y = fmaf(wv.z, xv[j].y, acc[2].y);
            acc[2].z = fmaf(wv.z, xv[j].z, acc[2].z); acc[2].w = fmaf(wv.z, xv[j].w, acc[2].w);
            acc[3].x = fmaf(wv.w, xv[j].x, acc[3].x); acc[3].y = fmaf(wv.w, xv[j].y, acc[3].y);
            acc[3].z = fmaf(wv.w, xv[j].z, acc[3].z); acc[3].w = fmaf(wv.w, xv[j].w, acc[3].w);
        }
    }
    float4 at = *(const float4*)(attn + (b << 14) + hw0 + (q4 << 2));
    #pragma unroll
    for (int u = 0; u < 4; ++u) {
        acc[u].x = (acc[u].x + b2v[u]) * at.x + bpv[u];
        acc[u].y = (acc[u].y + b2v[u]) * at.y + bpv[u];
        acc[u].z = (acc[u].z + b2v[u]) * at.z + bpv[u];
        acc[u].w = (acc[u].w + b2v[u]) * at.w + bpv[u];
    }
    const float* pb = p1 + (b << 19) + hw0 + (q4 << 2);
    #pragma unroll 1
    for (int cb = 0; cb < 4; ++cb) {
        float4 pv[8];
        #pragma unroll
        for (int j = 0; j < 8; ++j) pv[j] = *(const float4*)&pb[(cb * 8 + j) << 14];
        #pragma unroll
        for (int j = 0; j < 8; ++j) {
            float4 wv = *(const float4*)&wTp[(cb * 8 + j) * 20 + og * 4];
            acc[0].x = fmaf(wv.x, pv[j].x, acc[0].x); acc[0].y = fmaf(wv.x, pv[j].y, acc[0].y);
            acc[0].z = fmaf(wv.x, pv[j].z, acc[0].z); acc[0].w = fmaf(wv.x, pv[j].w, acc[0].w);
            acc[1].x = fmaf(wv.y, pv[j].x, acc[1].x); acc[1].y = fmaf(wv.y, pv[j].y, acc[1].y);
            acc[1].z = fmaf(wv.y, pv[j].z, acc[1].z); acc[1].w = fmaf(wv.y, pv[j].w, acc[1].w);
            acc[2].x = fmaf(wv.z, pv[j].x, acc[2].x); acc[2].y = fmaf(wv.z, pv[j].y, acc[2].y);
            acc[2].z = fmaf(wv.z, pv[j].z, acc[2].z); acc[2].w = fmaf(wv.z, pv[j].w, acc[2].w);
            acc[3].x = fmaf(wv.w, pv[j].x, acc[3].x); acc[3].y = fmaf(wv.w, pv[j].y, acc[3].y);
            acc[3].z = fmaf(wv.w, pv[j].z, acc[3].z); acc[3].w = fmaf(wv.w, pv[j].w, acc[3].w);
        }
    }
    #pragma unroll
    for (int u = 0; u < 4; ++u)
        *(float4*)(out + ((b * 128 + o0 + og * 4 + u) << 14) + hw0 + (q4 << 2)) = acc[u];
}

extern "C" void kernel_launch(void* const* d_in, const int* in_sizes, int n_in,
                              void* d_out, int out_size, void* d_ws, size_t ws_size,
                              hipStream_t stream) {
    const float* x   = (const float*)d_in[0];
    const float* w1  = (const float*)d_in[1];
    const float* b1  = (const float*)d_in[2];
    const float* a1  = (const float*)d_in[3];
    const float* wr  = (const float*)d_in[4];
    const float* br  = (const float*)d_in[5];
    const float* ws_ = (const float*)d_in[6];
    const float* bs  = (const float*)d_in[7];
    const float* a2  = (const float*)d_in[8];
    const float* w2  = (const float*)d_in[9];
    const float* b2  = (const float*)d_in[10];
    const float* wa  = (const float*)d_in[11];
    const float* ba  = (const float*)d_in[12];
    const float* wp1 = (const float*)d_in[13];
    const float* bp1 = (const float*)d_in[14];
    const float* ap  = (const float*)d_in[15];
    const float* wp2 = (const float*)d_in[16];
    const float* bp2 = (const float*)d_in[17];
    float* out = (float*)d_out;

    float* w = (float*)d_ws;
    float* ws_x1   = w;                        // 2*64*HW_
    float* ws_f    = ws_x1 + 2 * 64 * HW_;     // 2*32*HW_
    float* ws_x2   = ws_f  + 2 * 32 * HW_;     // 2*64*HW_ (holds prelu'd x2)
    float* ws_zp   = ws_x2 + 2 * 64 * HW_;     // 2*2*HW_
    float* ws_attn = ws_zp + 2 * 2 * HW_;      // NPX
    float* ws_p1   = ws_attn + NPX;            // 2*32*HW_

    hipLaunchKernelGGL(k_front, dim3(512), dim3(256), 0, stream,
                       x, w1, b1, a1, wr, br, ws_x1, ws_f, ws_zp);
    hipLaunchKernelGGL(k_mid2, dim3(896), dim3(256), 0, stream,
                       ws_x1, ws_f, ws_, bs, ws_x2, ws_zp,
                       wp1, bp1, ap, ws_p1, wa, ba, ws_attn, a2);
    hipLaunchKernelGGL(k_final, dim3(1024), dim3(256), 0, stream,
                       ws_x2, ws_p1, ws_attn, w2, b2, wp2, bp2, out);
}

// Round 14
// 175.232 us; speedup vs baseline: 1.0556x; 1.0556x over previous
//
#include <hip/hip_runtime.h>

#define HW_  16384   // H*W = 128*128
#define NPX  32768   // B*H*W

__device__ __forceinline__ float prelu_(float x, float a) { return x >= 0.f ? x : a * x; }

// ---------------- K_front: x1 = prelu(conv1(x)), f = relu(wr·x1), zp = zpool(f) ----
__global__ __launch_bounds__(256, 3) void k_front(const float* __restrict__ x,
        const float* __restrict__ w1, const float* __restrict__ b1,
        const float* __restrict__ a1p, const float* __restrict__ wr,
        const float* __restrict__ br, float* __restrict__ x1,
        float* __restrict__ f, float* __restrict__ zp) {
    __shared__ float sA[12544];        // 50.2 KB, two overlay regions
    float* xs  = sA;                   // 4096: [ch64][px64]
    float* wT1 = sA + 4096;            // 8448: [o64][c] stride 132
    int p0 = blockIdx.x << 6;
    int b = p0 >> 14, hw0 = p0 & 16383;

    for (int e = threadIdx.x; e < 8192; e += 256) {
        int o = e >> 7, c = e & 127;
        wT1[o * 132 + c] = w1[e];
    }
    int pq = threadIdx.x & 15;
    int og = threadIdx.x >> 4;
    const float a1 = a1p[0];
    float4 acc[4];
    #pragma unroll
    for (int u = 0; u < 4; ++u) { float bv = b1[og * 4 + u]; acc[u] = make_float4(bv, bv, bv, bv); }
    const float* xb = x + (b << 21) + hw0;
    #pragma unroll 1
    for (int half = 0; half < 2; ++half) {
        float4 xv[4];
        #pragma unroll
        for (int i = 0; i < 4; ++i) {
            int e = threadIdx.x + (i << 8);
            xv[i] = *(const float4*)&xb[((half * 64 + (e >> 4)) << 14) + ((e & 15) << 2)];
        }
        __syncthreads();
        #pragma unroll
        for (int i = 0; i < 4; ++i) {
            int e = threadIdx.x + (i << 8);
            *(float4*)&xs[((e >> 4) << 6) + ((e & 15) << 2)] = xv[i];
        }
        __syncthreads();
        #pragma unroll 4
        for (int c4 = 0; c4 < 16; ++c4) {
            float4 taps[4];
            #pragma unroll
            for (int j = 0; j < 4; ++j)
                taps[j] = *(const float4*)&xs[((c4 * 4 + j) << 6) + (pq << 2)];
            #pragma unroll
            for (int u = 0; u < 4; ++u) {
                float4 wv = *(const float4*)&wT1[(og * 4 + u) * 132 + half * 64 + c4 * 4];
                acc[u].x = fmaf(wv.x, taps[0].x, acc[u].x); acc[u].y = fmaf(wv.x, taps[0].y, acc[u].y);
                acc[u].z = fmaf(wv.x, taps[0].z, acc[u].z); acc[u].w = fmaf(wv.x, taps[0].w, acc[u].w);
                acc[u].x = fmaf(wv.y, taps[1].x, acc[u].x); acc[u].y = fmaf(wv.y, taps[1].y, acc[u].y);
                acc[u].z = fmaf(wv.y, taps[1].z, acc[u].z); acc[u].w = fmaf(wv.y, taps[1].w, acc[u].w);
                acc[u].x = fmaf(wv.z, taps[2].x, acc[u].x); acc[u].y = fmaf(wv.z, taps[2].y, acc[u].y);
                acc[u].z = fmaf(wv.z, taps[2].z, acc[u].z); acc[u].w = fmaf(wv.z, taps[2].w, acc[u].w);
                acc[u].x = fmaf(wv.w, taps[3].x, acc[u].x); acc[u].y = fmaf(wv.w, taps[3].y, acc[u].y);
                acc[u].z = fmaf(wv.w, taps[3].z, acc[u].z); acc[u].w = fmaf(wv.w, taps[3].w, acc[u].w);
            }
        }
    }
    float4 res[4];
    #pragma unroll
    for (int u = 0; u < 4; ++u) {
        res[u].x = prelu_(acc[u].x, a1); res[u].y = prelu_(acc[u].y, a1);
        res[u].z = prelu_(acc[u].z, a1); res[u].w = prelu_(acc[u].w, a1);
        *(float4*)(x1 + ((b * 64 + og * 4 + u) << 14) + hw0 + (pq << 2)) = res[u];
    }
    __syncthreads();
    float* x1t = sA;                   // 4352: [c64][px] stride 68
    float* wrT = sA + 4352;            // 2080: [fo32][c] stride 65
    float* ft  = sA + 6432;            // 2176: [fo32][px] stride 68
    #pragma unroll
    for (int u = 0; u < 4; ++u)
        *(float4*)&x1t[(og * 4 + u) * 68 + (pq << 2)] = res[u];
    for (int e = threadIdx.x; e < 2048; e += 256) {
        int fo = e >> 6, c = e & 63;
        wrT[fo * 65 + c] = wr[e];
    }
    __syncthreads();
    int pq2 = threadIdx.x & 15;
    int fg = threadIdx.x >> 4;
    float4 fa[2];
    #pragma unroll
    for (int u = 0; u < 2; ++u) { float bv = br[fg * 2 + u]; fa[u] = make_float4(bv, bv, bv, bv); }
    #pragma unroll 4
    for (int c = 0; c < 64; ++c) {
        float4 tap = *(const float4*)&x1t[c * 68 + (pq2 << 2)];
        #pragma unroll
        for (int u = 0; u < 2; ++u) {
            float wv = wrT[(fg * 2 + u) * 65 + c];
            fa[u].x = fmaf(wv, tap.x, fa[u].x);
            fa[u].y = fmaf(wv, tap.y, fa[u].y);
            fa[u].z = fmaf(wv, tap.z, fa[u].z);
            fa[u].w = fmaf(wv, tap.w, fa[u].w);
        }
    }
    #pragma unroll
    for (int u = 0; u < 2; ++u) {
        float4 r;
        r.x = fmaxf(fa[u].x, 0.f); r.y = fmaxf(fa[u].y, 0.f);
        r.z = fmaxf(fa[u].z, 0.f); r.w = fmaxf(fa[u].w, 0.f);
        *(float4*)(f + ((b * 32 + fg * 2 + u) << 14) + hw0 + (pq2 << 2)) = r;
        *(float4*)&ft[(fg * 2 + u) * 68 + (pq2 << 2)] = r;
    }
    __syncthreads();
    if (threadIdx.x < 64) {
        int px = threadIdx.x;
        float mx = ft[px], sm = ft[px];
        #pragma unroll
        for (int c = 1; c < 32; ++c) {
            float v = ft[c * 68 + px];
            mx = fmaxf(mx, v); sm += v;
        }
        zp[((b * 2 + 0) << 14) + hw0 + px] = mx;
        zp[((b * 2 + 1) << 14) + hw0 + px] = sm * (1.f / 32.f);
    }
}

// ---------------- K_mid2: [0,512) invol (writes prelu'd x2) ; [512,1024) psec ; [1024,1152) attn ----
// Reverted to the round-12 configuration (best known: 173.8 us total).
__global__ __launch_bounds__(256, 4) void k_mid2(const float* __restrict__ x1,
        const float* __restrict__ f, const float* __restrict__ ws_,
        const float* __restrict__ bs, float* __restrict__ x2,
        const float* __restrict__ zp, const float* __restrict__ wp1,
        const float* __restrict__ bp1, const float* __restrict__ app,
        float* __restrict__ p1, const float* __restrict__ wa,
        const float* __restrict__ ba, float* __restrict__ attn,
        const float* __restrict__ a2p) {
    __shared__ float smem[8448];           // 33.8 KB union
    if (blockIdx.x < 512) {
        // ---- involution: group g x 16x16 tile; epilogue folds prelu(.,a2)
        float* tile = smem;                // [16c][22r][24]
        int g = blockIdx.x >> 7;
        int t = blockIdx.x & 127;
        int b = t >> 6;
        int th = (t >> 3) & 7, tw = t & 7;
        int h0 = th * 16, w0 = tw * 16;
        const float* x1g = x1 + ((b * 64 + g * 16) << 14);
        #pragma unroll 1
        for (int rem = threadIdx.x; rem < 484; rem += 256) {
            int r = rem / 22, cl = rem - r * 22;
            int hh = h0 + r - 3, ww = w0 + cl - 3;
            bool ok = (hh >= 0 && hh < 128 && ww >= 0 && ww < 128);
            const float* src = x1g + (hh << 7) + ww;
            float v[16];
            #pragma unroll
            for (int c = 0; c < 16; ++c) v[c] = ok ? src[c << 14] : 0.f;
            float* dst = tile + r * 24 + cl;
            #pragma unroll
            for (int c = 0; c < 16; ++c) dst[c * 528] = v[c];
        }
        int lh = threadIdx.x >> 4, lw = threadIdx.x & 15;
        int hw = ((h0 + lh) << 7) + w0 + lw;
        float fv[32];
        const float* fp = f + (b << 19) + hw;
        #pragma unroll
        for (int c = 0; c < 32; ++c) fv[c] = fp[c << 14];
        __syncthreads();
        float acc[16];
        #pragma unroll
        for (int u = 0; u < 16; ++u) acc[u] = 0.f;
        const float* tap0 = tile + lh * 24 + lw;
        const float* wk = ws_ + g * 49 * 32;
        const float* bsg = bs + g * 49;
        #pragma unroll 1
        for (int di = 0; di < 7; ++di) {
            #pragma unroll 1
            for (int dj = 0; dj < 7; ++dj) {
                int kk = di * 7 + dj;
                float kwv = bsg[kk];
                const float* wkk = wk + kk * 32;
                #pragma unroll
                for (int c = 0; c < 32; ++c) kwv = fmaf(wkk[c], fv[c], kwv);
                const float* tp = tap0 + di * 24 + dj;
                #pragma unroll
                for (int u = 0; u < 16; ++u)
                    acc[u] = fmaf(kwv, tp[u * 528], acc[u]);
            }
        }
        const float a2 = a2p[0];
        float* op = x2 + ((b * 64 + g * 16) << 14) + hw;
        #pragma unroll
        for (int u = 0; u < 16; ++u) op[u << 14] = prelu_(acc[u], a2);
    } else if (blockIdx.x < 1024) {
        // ---- psec conv3x3
        float* fs = smem;                  // 6080
        float* wT = smem + 6080;           // 2320: [o16][idx144] stride 145
        int bid = blockIdx.x - 512;
        int half = bid >> 8;
        int t = bid & 255;
        int b = t >> 7;
        int tl = t & 127;
        int th = tl >> 3, tw = tl & 7;
        int h0 = th * 8, w0 = tw * 16;
        int o0 = half * 16;
        const float* fb = f + (b << 19);
        #pragma unroll 1
        for (int rem = threadIdx.x; rem < 180; rem += 256) {
            int r = rem / 18, cl = rem - r * 18;
            int hh = h0 + r - 1, ww = w0 + cl - 1;
            bool ok = (hh >= 0 && hh < 128 && ww >= 0 && ww < 128);
            const float* src = fb + (hh << 7) + ww;
            float* dst = fs + r * 19 + cl;
            #pragma unroll 1
            for (int cb = 0; cb < 4; ++cb) {
                float v[8];
                #pragma unroll
                for (int c = 0; c < 8; ++c) v[c] = ok ? src[(cb * 8 + c) << 14] : 0.f;
                #pragma unroll
                for (int c = 0; c < 8; ++c) dst[(cb * 8 + c) * 190] = v[c];
            }
        }
        int pxq = threadIdx.x & 31;
        int rowq = pxq >> 2, colq = pxq & 3;
        int oh = threadIdx.x >> 5;
        const float ap = app[0];
        float acc[2][4];
        #pragma unroll
        for (int o = 0; o < 2; ++o) {
            float bv = bp1[o0 + oh * 2 + o];
            #pragma unroll
            for (int px = 0; px < 4; ++px) acc[o][px] = bv;
        }
        const float* fsb = fs + rowq * 19 + colq * 4;
        #pragma unroll 1
        for (int cih = 0; cih < 2; ++cih) {
            __syncthreads();
            #pragma unroll 1
            for (int e = threadIdx.x; e < 2304; e += 256) {
                int o = e / 144, i = e - o * 144;
                wT[o * 145 + i] = wp1[(o0 + o) * 288 + cih * 144 + i];
            }
            __syncthreads();
            #pragma unroll 1
            for (int cl_ = 0; cl_ < 16; ++cl_) {
                int ci = cih * 16 + cl_;
                float tap[3][6];
                const float* base = fsb + ci * 190;
                #pragma unroll
                for (int r = 0; r < 3; ++r)
                    #pragma unroll
                    for (int j = 0; j < 6; ++j)
                        tap[r][j] = base[r * 19 + j];
                #pragma unroll
                for (int ki = 0; ki < 3; ++ki)
                    #pragma unroll
                    for (int kj = 0; kj < 3; ++kj) {
                        int idx = cl_ * 9 + ki * 3 + kj;
                        float w0v = wT[(oh * 2 + 0) * 145 + idx];
                        float w1v = wT[(oh * 2 + 1) * 145 + idx];
                        #pragma unroll
                        for (int px = 0; px < 4; ++px) {
                            float tv = tap[ki][px + kj];
                            acc[0][px] = fmaf(w0v, tv, acc[0][px]);
                            acc[1][px] = fmaf(w1v, tv, acc[1][px]);
                        }
                    }
            }
        }
        int hw = ((h0 + rowq) << 7) + w0 + colq * 4;
        #pragma unroll
        for (int o = 0; o < 2; ++o) {
            float4 r;
            r.x = prelu_(acc[o][0], ap); r.y = prelu_(acc[o][1], ap);
            r.z = prelu_(acc[o][2], ap); r.w = prelu_(acc[o][3], ap);
            *(float4*)(p1 + ((b * 32 + o0 + oh * 2 + o) << 14) + hw) = r;
        }
    } else {
        // ---- attn
        float* zs = smem;
        int t = blockIdx.x - 1024;
        int b = t >> 6;
        int tile = t & 63;
        int th = tile >> 3, tw = tile & 7;
        int h0 = th * 16, w0 = tw * 16;
        const float* zb = zp + (b << 15);
        #pragma unroll 1
        for (int rem = threadIdx.x; rem < 484; rem += 256) {
            int r = rem / 22, cl = rem - r * 22;
            int hh = h0 + r - 3, ww = w0 + cl - 3;
            bool ok = (hh >= 0 && hh < 128 && ww >= 0 && ww < 128);
            const float* src = zb + (hh << 7) + ww;
            float v0 = ok ? src[0] : 0.f;
            float v1 = ok ? src[HW_] : 0.f;
            zs[r * 23 + cl] = v0;
            zs[506 + r * 23 + cl] = v1;
        }
        __syncthreads();
        int lh = threadIdx.x >> 4, lw = threadIdx.x & 15;
        float acc = ba[0];
        #pragma unroll
        for (int c = 0; c < 2; ++c) {
            const float* zc = &zs[c * 506 + lh * 23 + lw];
            #pragma unroll
            for (int i = 0; i < 7; ++i)
                #pragma unroll
                for (int j = 0; j < 7; ++j)
                    acc = fmaf(wa[c * 49 + i * 7 + j], zc[i * 23 + j], acc);
        }
        attn[(b << 14) + ((h0 + lh) << 7) + w0 + lw] = 1.f / (1.f + expf(-acc));
    }
}

// ---------------- K_final: global-streaming (round-12 version) ----------
__global__ __launch_bounds__(256, 4) void k_final(const float* __restrict__ x2p,
        const float* __restrict__ p1, const float* __restrict__ attn,
        const float* __restrict__ w2, const float* __restrict__ b2,
        const float* __restrict__ wp2, const float* __restrict__ bp2,
        float* __restrict__ out) {
    __shared__ float wT2[64 * 20];     // [c][o] stride 20 (b128-aligned)
    __shared__ float wTp[32 * 20];
    int split = blockIdx.x >> 7;       // 0..7, block-uniform
    int tile = blockIdx.x & 127;       // 256-px tiles
    int p0 = tile << 8;
    int b = p0 >> 14, hw0 = p0 & 16383;
    int o0 = split * 16;

    for (int e = threadIdx.x; e < 1024; e += 256) {
        int o = e & 15, c = e >> 4;
        wT2[c * 20 + o] = w2[(o0 + o) * 64 + c];
    }
    for (int e = threadIdx.x; e < 512; e += 256) {
        int o = e & 15, c = e >> 4;
        wTp[c * 20 + o] = wp2[(o0 + o) * 32 + c];
    }
    int q4 = threadIdx.x & 63;         // px-quad 0..63 (256 px)
    int og = threadIdx.x >> 6;         // 0..3, wave-uniform
    float b2v[4], bpv[4];
    #pragma unroll
    for (int u = 0; u < 4; ++u) { b2v[u] = b2[o0 + og * 4 + u]; bpv[u] = bp2[o0 + og * 4 + u]; }
    float4 acc[4];
    #pragma unroll
    for (int u = 0; u < 4; ++u) acc[u] = make_float4(0.f, 0.f, 0.f, 0.f);
    __syncthreads();

    const float* xb = x2p + (b << 20) + hw0 + (q4 << 2);   // ch stride HW_
    #pragma unroll 1
    for (int cb = 0; cb < 8; ++cb) {
        float4 xv[8];
        #pragma unroll
        for (int j = 0; j < 8; ++j) xv[j] = *(const float4*)&xb[(cb * 8 + j) << 14];
        #pragma unroll
        for (int j = 0; j < 8; ++j) {
            float4 wv = *(const float4*)&wT2[(cb * 8 + j) * 20 + og * 4];  // broadcast
            acc[0].x = fmaf(wv.x, xv[j].x, acc[0].x); acc[0].y = fmaf(wv.x, xv[j].y, acc[0].y);
            acc[0].z = fmaf(wv.x, xv[j].z, acc[0].z); acc[0].w = fmaf(wv.x, xv[j].w, acc[0].w);
            acc[1].x = fmaf(wv.y, xv[j].x, acc[1].x); acc[1].y = fmaf(wv.y, xv[j].y, acc[1].y);
            acc[1].z = fmaf(wv.y, xv[j].z, acc[1].z); acc[1].w = fmaf(wv.y, xv[j].w, acc[1].w);
            acc[2].x = fmaf(wv.z, xv[j].x, acc[2].x); acc[2].y = fmaf(wv.z, xv[j].y, acc[2].y);
            acc[2].z = fmaf(wv.z, xv[j].z, acc[2].z); acc[2].w = fmaf(wv.z, xv[j].w, acc[2].w);
            acc[3].x = fmaf(wv.w, xv[j].x, acc[3].x); acc[3].y = fmaf(wv.w, xv[j].y, acc[3].y);
            acc[3].z = fmaf(wv.w, xv[j].z, acc[3].z); acc[3].w = fmaf(wv.w, xv[j].w, acc[3].w);
        }
    }
    float4 at = *(const float4*)(attn + (b << 14) + hw0 + (q4 << 2));
    #pragma unroll
    for (int u = 0; u < 4; ++u) {
        acc[u].x = (acc[u].x + b2v[u]) * at.x + bpv[u];
        acc[u].y = (acc[u].y + b2v[u]) * at.y + bpv[u];
        acc[u].z = (acc[u].z + b2v[u]) * at.z + bpv[u];
        acc[u].w = (acc[u].w + b2v[u]) * at.w + bpv[u];
    }
    const float* pb = p1 + (b << 19) + hw0 + (q4 << 2);
    #pragma unroll 1
    for (int cb = 0; cb < 4; ++cb) {
        float4 pv[8];
        #pragma unroll
        for (int j = 0; j < 8; ++j) pv[j] = *(const float4*)&pb[(cb * 8 + j) << 14];
        #pragma unroll
        for (int j = 0; j < 8; ++j) {
            float4 wv = *(const float4*)&wTp[(cb * 8 + j) * 20 + og * 4];
            acc[0].x = fmaf(wv.x, pv[j].x, acc[0].x); acc[0].y = fmaf(wv.x, pv[j].y, acc[0].y);
            acc[0].z = fmaf(wv.x, pv[j].z, acc[0].z); acc[0].w = fmaf(wv.x, pv[j].w, acc[0].w);
            acc[1].x = fmaf(wv.y, pv[j].x, acc[1].x); acc[1].y = fmaf(wv.y, pv[j].y, acc[1].y);
            acc[1].z = fmaf(wv.y, pv[j].z, acc[1].z); acc[1].w = fmaf(wv.y, pv[j].w, acc[1].w);
            acc[2].x = fmaf(wv.z, pv[j].x, acc[2].x); acc[2].y = fmaf(wv.z, pv[j].y, acc[2].y);
            acc[2].z = fmaf(wv.z, pv[j].z, acc[2].z); acc[2].w = fmaf(wv.z, pv[j].w, acc[2].w);
            acc[3].x = fmaf(wv.w, pv[j].x, acc[3].x); acc[3].y = fmaf(wv.w, pv[j].y, acc[3].y);
            acc[3].z = fmaf(wv.w, pv[j].z, acc[3].z); acc[3].w = fmaf(wv.w, pv[j].w, acc[3].w);
        }
    }
    #pragma unroll
    for (int u = 0; u < 4; ++u)
        *(float4*)(out + ((b * 128 + o0 + og * 4 + u) << 14) + hw0 + (q4 << 2)) = acc[u];
}

extern "C" void kernel_launch(void* const* d_in, const int* in_sizes, int n_in,
                              void* d_out, int out_size, void* d_ws, size_t ws_size,
                              hipStream_t stream) {
    const float* x   = (const float*)d_in[0];
    const float* w1  = (const float*)d_in[1];
    const float* b1  = (const float*)d_in[2];
    const float* a1  = (const float*)d_in[3];
    const float* wr  = (const float*)d_in[4];
    const float* br  = (const float*)d_in[5];
    const float* ws_ = (const float*)d_in[6];
    const float* bs  = (const float*)d_in[7];
    const float* a2  = (const float*)d_in[8];
    const float* w2  = (const float*)d_in[9];
    const float* b2  = (const float*)d_in[10];
    const float* wa  = (const float*)d_in[11];
    const float* ba  = (const float*)d_in[12];
    const float* wp1 = (const float*)d_in[13];
    const float* bp1 = (const float*)d_in[14];
    const float* ap  = (const float*)d_in[15];
    const float* wp2 = (const float*)d_in[16];
    const float* bp2 = (const float*)d_in[17];
    float* out = (float*)d_out;

    float* w = (float*)d_ws;
    float* ws_x1   = w;                        // 2*64*HW_
    float* ws_f    = ws_x1 + 2 * 64 * HW_;     // 2*32*HW_
    float* ws_x2   = ws_f  + 2 * 32 * HW_;     // 2*64*HW_ (holds prelu'd x2)
    float* ws_zp   = ws_x2 + 2 * 64 * HW_;     // 2*2*HW_
    float* ws_attn = ws_zp + 2 * 2 * HW_;      // NPX
    float* ws_p1   = ws_attn + NPX;            // 2*32*HW_

    hipLaunchKernelGGL(k_front, dim3(512), dim3(256), 0, stream,
                       x, w1, b1, a1, wr, br, ws_x1, ws_f, ws_zp);
    hipLaunchKernelGGL(k_mid2, dim3(1152), dim3(256), 0, stream,
                       ws_x1, ws_f, ws_, bs, ws_x2, ws_zp,
                       wp1, bp1, ap, ws_p1, wa, ba, ws_attn, a2);
    hipLaunchKernelGGL(k_final, dim3(1024), dim3(256), 0, stream,
                       ws_x2, ws_p1, ws_attn, w2, b2, wp2, bp2, out);
}